// Round 3
// baseline (581.451 us; speedup 1.0000x reference)
//
#include <hip/hip_runtime.h>

typedef short bf8 __attribute__((ext_vector_type(8)));
typedef float f4 __attribute__((ext_vector_type(4)));

#define DEV static __device__ __forceinline__

DEV short f2bf(float f) {
  unsigned u = __float_as_uint(f);
  u += 0x7FFF + ((u >> 16) & 1);   // RNE f32 -> bf16
  return (short)(u >> 16);
}

DEV f4 mfma16(bf8 a, bf8 b, f4 c) {
  return __builtin_amdgcn_mfma_f32_16x16x32_bf16(a, b, c, 0, 0, 0);
}

// ---------------- workspace layout (units: shorts / bf16 elems) ----------------
// Qp: [4][16][1024][64]   projected queries
// Kp: [4][16][1088][64]   projected keys + persistent rows + zero pad
// Vt: [4][16][64][1088]   projected values, TRANSPOSED (d-major) + persistent + pad
// Wo_bf: [1024][1024]
// AO: [4][1024][1024]     attention output (pre output-projection)
#define QP_OFF 0
#define QP_SZ  (4*16*1024*64)
#define KP_OFF (QP_OFF + QP_SZ)
#define KP_SZ  (4*16*1088*64)
#define VT_OFF (KP_OFF + KP_SZ)
#define VT_SZ  (4*16*1088*64)
#define WO_OFF (VT_OFF + VT_SZ)
#define WO_SZ  (1024*1024)
#define AO_OFF (WO_OFF + WO_SZ)

// =============== Phase 1a: per-head 64x64 projections (Q,K,V) ===============
// GEMM rows are (n,l,h) with contiguous 64-f32 row data. 16-row groups -> MFMA.
// type 0: queries->Qp, 1: keys->Kp, 2: values->Vt (transposed via LDS).
__global__ __launch_bounds__(256) void k_proj(
    const float* __restrict__ vals, const float* __restrict__ keys,
    const float* __restrict__ qrys,
    const float* __restrict__ Wv, const float* __restrict__ Wk,
    const float* __restrict__ Wq,
    short* __restrict__ ws)
{
  short* Qp = ws + QP_OFF;
  short* Kp = ws + KP_OFF;
  short* Vt = ws + VT_OFF;
  __shared__ float ldsT[4][16][68];

  const int tid = threadIdx.x, wave = tid >> 6, lane = tid & 63;
  const int l16 = lane & 15, lh = lane >> 4;
  const int gbase = (blockIdx.x * 4 + wave) * 4;   // 4 groups per wave
  const int type = gbase >> 12;                    // uniform per block (16 | 4096)
  const f4 fzero = {0.f, 0.f, 0.f, 0.f};

  const float* in;
  const float* W;
  if (type == 0)      { in = qrys; W = Wq; }
  else if (type == 1) { in = keys; W = Wk; }
  else                { in = vals; W = Wv; }

  // W fragments: B[k=d_in][n=d_out] = W[d_out][d_in] -> lane reads W row (ct*16+l16)
  bf8 wf[4][2];
#pragma unroll
  for (int ct = 0; ct < 4; ++ct)
#pragma unroll
    for (int kh = 0; kh < 2; ++kh) {
      const float* p = W + (ct*16 + l16)*64 + kh*32 + lh*8;
      bf8 t;
#pragma unroll
      for (int j = 0; j < 8; ++j) t[j] = f2bf(p[j]);
      wf[ct][kh] = t;
    }

  for (int i = 0; i < 4; ++i) {
    const int gi = (gbase + i) & 4095;
    if (type < 2) {
      // rows = 16 heads of token gi; A row = in[token*1024 + h*64 ...]
      const int n = gi >> 10, l = gi & 1023;
      const float* arow = in + gi*1024 + l16*64 + lh*8;
      bf8 a0, a1;
#pragma unroll
      for (int j = 0; j < 8; ++j) { a0[j] = f2bf(arow[j]); a1[j] = f2bf(arow[32 + j]); }
#pragma unroll
      for (int ct = 0; ct < 4; ++ct) {
        f4 e = fzero;
        e = mfma16(a0, wf[ct][0], e);
        e = mfma16(a1, wf[ct][1], e);
#pragma unroll
        for (int jj = 0; jj < 4; ++jj) {
          const int h = lh*4 + jj, c = ct*16 + l16;
          if (type == 0) Qp[((n*16 + h)*1024 + l)*64 + c] = f2bf(e[jj]);
          else           Kp[((n*16 + h)*1088 + l)*64 + c] = f2bf(e[jj]);
        }
      }
    } else {
      // V: rows = 16 consecutive tokens for fixed (n,h); transpose tile via LDS
      const int nh = gi >> 6, lt = (gi & 63) * 16;
      const int n = nh >> 4, h = nh & 15;
      const float* arow = in + (n*1024 + lt + l16)*1024 + h*64 + lh*8;
      bf8 a0, a1;
#pragma unroll
      for (int j = 0; j < 8; ++j) { a0[j] = f2bf(arow[j]); a1[j] = f2bf(arow[32 + j]); }
#pragma unroll
      for (int ct = 0; ct < 4; ++ct) {
        f4 e = fzero;
        e = mfma16(a0, wf[ct][0], e);
        e = mfma16(a1, wf[ct][1], e);
#pragma unroll
        for (int jj = 0; jj < 4; ++jj)
          ldsT[wave][lh*4 + jj][ct*16 + l16] = e[jj];
      }
      __syncthreads();
      // lane = d (0..63); write Vt row d, 16 contiguous token cols
      short* vb = Vt + (nh*64 + lane)*1088 + lt;
      bf8 t0, t1;
#pragma unroll
      for (int j = 0; j < 8; ++j) {
        t0[j] = f2bf(ldsT[wave][j][lane]);
        t1[j] = f2bf(ldsT[wave][8 + j][lane]);
      }
      *(bf8*)vb = t0;
      *(bf8*)(vb + 8) = t1;
      __syncthreads();
    }
  }
}

// =============== Phase 1b: persistent rows, zero pads, Wo -> bf16 ===============
__global__ __launch_bounds__(256) void k_fill(
    const float* __restrict__ Wo, const float* __restrict__ pkeys,
    const float* __restrict__ pvals, short* __restrict__ ws)
{
  short* Kp = ws + KP_OFF;
  short* Vt = ws + VT_OFF;
  short* Wo_bf = ws + WO_OFF;
  const int NT = 1048576 + 65536 + 196608 + 65536 + 196608;
  for (int i = blockIdx.x*blockDim.x + threadIdx.x; i < NT; i += gridDim.x*blockDim.x) {
    int x = i;
    if (x < 1048576) { Wo_bf[x] = f2bf(Wo[x]); continue; }
    x -= 1048576;
    if (x < 65536) {  // Kp persistent rows (raw p_keys, broadcast over n,h)
      const int d = x & 63, p = (x >> 6) & 15, nh = x >> 10;
      Kp[(nh*1088 + 1024 + p)*64 + d] = f2bf(pkeys[p*64 + d]);
      continue;
    }
    x -= 65536;
    if (x < 196608) {  // Kp zero pad rows 1040..1087
      const int d = x & 63, r = x >> 6, z = r % 48, nh = r / 48;
      Kp[(nh*1088 + 1040 + z)*64 + d] = 0;
      continue;
    }
    x -= 196608;
    if (x < 65536) {  // Vt persistent cols
      const int d = x & 63, p = (x >> 6) & 15, nh = x >> 10;
      Vt[(nh*64 + d)*1088 + 1024 + p] = f2bf(pvals[p*64 + d]);
      continue;
    }
    x -= 65536;
    {  // Vt zero pad cols
      const int d = x & 63, r = x >> 6, z = r % 48, nh = r / 48;
      Vt[(nh*64 + d)*1088 + 1040 + z] = 0;
    }
  }
}

// =============== Phase 2: fused talking-heads attention ===============
// grid = n(4) x qtile(64); block = 4 waves. Wave w owns heads/rows 4w..4w+3.
// Sweep 1: Z[h,q] = sum_k exp(S). Sweep 2: recompute S, p=exp(S)/Z, th_post mix, PV.
#define HPITCH 24
#define KPITCH 72
#define LDSE_N (16*64*HPITCH + 16)
__global__ __launch_bounds__(256) void k_attn(
    const int* __restrict__ mask, const float* __restrict__ th_pre,
    const float* __restrict__ th_post, short* ws)
{
  const short* Qp = ws + QP_OFF;
  const short* Kp = ws + KP_OFF;
  const short* Vt = ws + VT_OFF;
  short* AO = ws + AO_OFF;

  __shared__ __align__(16) short ldsE[LDSE_N];        // [elem=(q,k)][h] bf16
  __shared__ __align__(16) short ldsA[16*16*KPITCH];  // [o][q][k] bf16

  const int tid = threadIdx.x, wave = tid >> 6, lane = tid & 63;
  const int l16 = lane & 15, lh = lane >> 4;
  const int n = blockIdx.x >> 6, qt = blockIdx.x & 63, q0 = qt * 16;
  const f4 fzero = {0.f, 0.f, 0.f, 0.f};

  // Zero ldsE ONCE (incl. pad heads 16..23 and tail): the mix MFMAs read
  // k=16..31 B-elements there with zero A-coefficients, and 0 x NaN-garbage
  // would poison the accumulate (IEEE 0*NaN=NaN). QK_STAGE never writes pad.
  for (int i = tid; i < LDSE_N; i += 256) ldsE[i] = 0;
  __syncthreads();

  // talking-heads A-fragments, zero-padded to K=32 (lanes lh>=2 hold zeros)
  bf8 thA[2];
  {
    bf8 z;
#pragma unroll
    for (int j = 0; j < 8; ++j) z[j] = 0;
    thA[0] = z; thA[1] = z;
    if (lh < 2) {
      const float* r0 = th_pre  + l16*16 + lh*8;
      const float* r1 = th_post + l16*16 + lh*8;
      bf8 t0, t1;
#pragma unroll
      for (int j = 0; j < 8; ++j) { t0[j] = f2bf(r0[j]); t1[j] = f2bf(r1[j]); }
      thA[0] = t0; thA[1] = t1;
    }
  }
  // mixed ALiBi slopes for o = lh*4+jj (mix-output row held by this lane)
  float mslope[4];
#pragma unroll
  for (int jj = 0; jj < 4; ++jj) {
    const int o = lh*4 + jj;
    float s = 0.f;
    for (int h = 0; h < 16; ++h) s += th_pre[o*16 + h] * exp2f(-(float)(h + 1));
    mslope[jj] = s;
  }

  // Q fragments for the wave's 4 heads (reused across all k)
  bf8 qf[4][2];
#pragma unroll
  for (int hh = 0; hh < 4; ++hh)
#pragma unroll
    for (int kh = 0; kh < 2; ++kh)
      qf[hh][kh] = *(const bf8*)(Qp + ((n*16 + wave*4 + hh)*1024 + q0 + l16)*64 + kh*32 + lh*8);

  const int* maskn = mask + n*1024;

#define QK_STAGE() \
  { \
    _Pragma("unroll") \
    for (int hh = 0; hh < 4; ++hh) { \
      const short* Kb = Kp + ((n*16 + wave*4 + hh)*1088 + k0 + l16)*64 + lh*8; \
      _Pragma("unroll") \
      for (int kt = 0; kt < 4; ++kt) { \
        f4 e = fzero; \
        e = mfma16(qf[hh][0], *(const bf8*)(Kb + kt*16*64), e); \
        e = mfma16(qf[hh][1], *(const bf8*)(Kb + kt*16*64 + 32), e); \
        _Pragma("unroll") \
        for (int jj = 0; jj < 4; ++jj) \
          ldsE[((lh*4 + jj)*64 + kt*16 + l16)*HPITCH + wave*4 + hh] = f2bf(e[jj]); \
      } \
    } \
  }

  // ---------------- sweep 1: Z ----------------
  float Zp[4][4];
#pragma unroll
  for (int a = 0; a < 4; ++a)
#pragma unroll
    for (int b = 0; b < 4; ++b) Zp[a][b] = 0.f;

  for (int kb = 0; kb < 17; ++kb) {
    const int k0 = kb * 64;
    QK_STAGE();
    __syncthreads();
#pragma unroll
    for (int qi = 0; qi < 4; ++qi) {
      const int q = wave*4 + qi, ig = q0 + q;
#pragma unroll
      for (int ks = 0; ks < 4; ++ks) {
        const int elem = q*64 + ks*16 + l16;
        bf8 Bf = *(const bf8*)(ldsE + elem*HPITCH + lh*8);
        f4 s = mfma16(thA[0], Bf, fzero);
        const int kg = k0 + ks*16 + l16;
        float ad = 0.f; bool dead;
        if (kg < 1024) { dead = (maskn[kg] == 0); ad = fabsf((float)(ig - kg)); }
        else           { dead = (kg >= 1040); }
#pragma unroll
        for (int jj = 0; jj < 4; ++jj) {
          float v = s[jj] - ad * mslope[jj];
          v = dead ? -1e4f : v;
          Zp[jj][qi] += __expf(v * 0.03125f);
        }
      }
    }
    __syncthreads();
  }
  // reduce Z across the 16 k-col lanes; all lanes get their (o,q) inverse
  float invZ[4][4];
#pragma unroll
  for (int jj = 0; jj < 4; ++jj)
#pragma unroll
    for (int qi = 0; qi < 4; ++qi) {
      float z = Zp[jj][qi];
      z += __shfl_xor(z, 1); z += __shfl_xor(z, 2);
      z += __shfl_xor(z, 4); z += __shfl_xor(z, 8);
      invZ[jj][qi] = 1.f / z;
    }

  // ---------------- sweep 2: normalize, th_post mix, PV ----------------
  f4 acc[4][4];
#pragma unroll
  for (int a = 0; a < 4; ++a)
#pragma unroll
    for (int b = 0; b < 4; ++b) acc[a][b] = fzero;

  for (int kb = 0; kb < 17; ++kb) {
    const int k0 = kb * 64;
    QK_STAGE();
    __syncthreads();
#pragma unroll
    for (int qi = 0; qi < 4; ++qi) {
      const int q = wave*4 + qi, ig = q0 + q;
#pragma unroll
      for (int ks = 0; ks < 4; ++ks) {
        const int elem = q*64 + ks*16 + l16;
        bf8 Bf = *(const bf8*)(ldsE + elem*HPITCH + lh*8);
        f4 s = mfma16(thA[0], Bf, fzero);
        const int kg = k0 + ks*16 + l16;
        float ad = 0.f; bool dead;
        if (kg < 1024) { dead = (maskn[kg] == 0); ad = fabsf((float)(ig - kg)); }
        else           { dead = (kg >= 1040); }
        float p[4];
#pragma unroll
        for (int jj = 0; jj < 4; ++jj) {
          float v = s[jj] - ad * mslope[jj];
          v = dead ? -1e4f : v;
          p[jj] = __expf(v * 0.03125f) * invZ[jj][qi];
        }
        // build mix2 B-frag: lane needs p over o' = lh*8..lh*8+7 for its elem col
        const int pk0 = ((int)(unsigned short)f2bf(p[1]) << 16) | (unsigned short)f2bf(p[0]);
        const int pk1 = ((int)(unsigned short)f2bf(p[3]) << 16) | (unsigned short)f2bf(p[2]);
        const int s0 = (lh*2)*16 + l16, s1 = (lh*2 + 1)*16 + l16;
        union { int w[4]; bf8 v; } mb;
        mb.w[0] = __shfl(pk0, s0); mb.w[1] = __shfl(pk1, s0);
        mb.w[2] = __shfl(pk0, s1); mb.w[3] = __shfl(pk1, s1);
        f4 a = mfma16(thA[1], mb.v, fzero);
#pragma unroll
        for (int jj = 0; jj < 4; ++jj)
          ldsA[((lh*4 + jj)*16 + q)*KPITCH + ks*16 + l16] = f2bf(a[jj]);
      }
    }
    __syncthreads();
    // PV for the wave's 4 output heads
#pragma unroll
    for (int hh = 0; hh < 4; ++hh) {
      const int o = wave*4 + hh;
      const short* Vb = Vt + (n*16 + o)*64*1088 + k0;
#pragma unroll
      for (int kkh = 0; kkh < 2; ++kkh) {
        bf8 af = *(const bf8*)(ldsA + (o*16 + l16)*KPITCH + kkh*32 + lh*8);
#pragma unroll
        for (int dt = 0; dt < 4; ++dt) {
          bf8 vf = *(const bf8*)(Vb + (dt*16 + l16)*1088 + kkh*32 + lh*8);
          acc[hh][dt] = mfma16(af, vf, acc[hh][dt]);
        }
      }
    }
  }

  // store attention output [n][q][o*64+d] bf16
#pragma unroll
  for (int hh = 0; hh < 4; ++hh)
#pragma unroll
    for (int dt = 0; dt < 4; ++dt)
#pragma unroll
      for (int jj = 0; jj < 4; ++jj)
        AO[(n*1024 + q0 + lh*4 + jj)*1024 + (wave*4 + hh)*64 + dt*16 + l16] =
            f2bf(acc[hh][dt][jj]);
}

// =============== Phase 3: out = AO @ Wo^T + bo (f32 out) ===============
__global__ __launch_bounds__(256) void k_out(
    const short* __restrict__ ws, const float* __restrict__ bo,
    float* __restrict__ out)
{
  const short* A  = ws + AO_OFF;
  const short* Wb = ws + WO_OFF;
  const int tid = threadIdx.x, wave = tid >> 6, lane = tid & 63;
  const int l16 = lane & 15, lh = lane >> 4;
  const int r0 = blockIdx.x*64 + wave*16, c0 = blockIdx.y*64;
  const f4 fzero = {0.f, 0.f, 0.f, 0.f};
  f4 acc[4];
#pragma unroll
  for (int ct = 0; ct < 4; ++ct) acc[ct] = fzero;

  const short* Ar = A  + (r0 + l16)*1024 + lh*8;
  const short* Wr = Wb + (c0 + l16)*1024 + lh*8;
  for (int kk = 0; kk < 1024; kk += 32) {
    bf8 af = *(const bf8*)(Ar + kk);
#pragma unroll
    for (int ct = 0; ct < 4; ++ct) {
      bf8 bf = *(const bf8*)(Wr + ct*16*1024 + kk);
      acc[ct] = mfma16(af, bf, acc[ct]);
    }
  }
#pragma unroll
  for (int ct = 0; ct < 4; ++ct) {
    const int c = c0 + ct*16 + l16;
    const float b = bo[c];
#pragma unroll
    for (int jj = 0; jj < 4; ++jj)
      out[(r0 + lh*4 + jj)*1024 + c] = acc[ct][jj] + b;
  }
}

extern "C" void kernel_launch(void* const* d_in, const int* in_sizes, int n_in,
                              void* d_out, int out_size, void* d_ws, size_t ws_size,
                              hipStream_t stream) {
  const float* vals = (const float*)d_in[0];
  const float* keys = (const float*)d_in[1];
  const float* qrys = (const float*)d_in[2];
  const int*   mask = (const int*)d_in[3];
  const float* Wv   = (const float*)d_in[4];
  const float* Wk   = (const float*)d_in[5];
  const float* Wq   = (const float*)d_in[6];
  const float* Wo   = (const float*)d_in[7];
  const float* bo   = (const float*)d_in[8];
  const float* thp  = (const float*)d_in[9];
  const float* tho  = (const float*)d_in[10];
  const float* pk   = (const float*)d_in[11];
  const float* pv   = (const float*)d_in[12];
  short* ws = (short*)d_ws;
  float* out = (float*)d_out;

  k_proj<<<768, 256, 0, stream>>>(vals, keys, qrys, Wv, Wk, Wq, ws);
  k_fill<<<512, 256, 0, stream>>>(Wo, pk, pv, ws);
  k_attn<<<256, 256, 0, stream>>>(mask, thp, tho, ws);
  k_out<<<dim3(64, 16), 256, 0, stream>>>(ws, bo, out);
}

// Round 4
// 443.297 us; speedup vs baseline: 1.3116x; 1.3116x over previous
//
#include <hip/hip_runtime.h>

typedef short bf8 __attribute__((ext_vector_type(8)));
typedef float f4 __attribute__((ext_vector_type(4)));

#define DEV static __device__ __forceinline__

DEV short f2bf(float f) {
  unsigned u = __float_as_uint(f);
  u += 0x7FFF + ((u >> 16) & 1);   // RNE f32 -> bf16
  return (short)(u >> 16);
}

DEV f4 mfma16(bf8 a, bf8 b, f4 c) {
  return __builtin_amdgcn_mfma_f32_16x16x32_bf16(a, b, c, 0, 0, 0);
}

// ---------------- workspace layout (units: shorts / bf16 elems) ----------------
// Qp: [4][16][1024][64]   projected queries
// Kp: [4][16][1088][64]   projected keys + persistent rows + zero pad
// Vt: [4][16][64][1088]   projected values, TRANSPOSED (d-major) + persistent + pad
// Wo_bf: [1024][1024]
// AO: [4][1024][1024]     attention output (pre output-projection)
#define QP_OFF 0
#define QP_SZ  (4*16*1024*64)
#define KP_OFF (QP_OFF + QP_SZ)
#define KP_SZ  (4*16*1088*64)
#define VT_OFF (KP_OFF + KP_SZ)
#define VT_SZ  (4*16*1088*64)
#define WO_OFF (VT_OFF + VT_SZ)
#define WO_SZ  (1024*1024)
#define AO_OFF (WO_OFF + WO_SZ)

// =============== Phase 1a: per-head 64x64 projections (Q,K,V) ===============
__global__ __launch_bounds__(256) void k_proj(
    const float* __restrict__ vals, const float* __restrict__ keys,
    const float* __restrict__ qrys,
    const float* __restrict__ Wv, const float* __restrict__ Wk,
    const float* __restrict__ Wq,
    short* __restrict__ ws)
{
  short* Qp = ws + QP_OFF;
  short* Kp = ws + KP_OFF;
  short* Vt = ws + VT_OFF;
  __shared__ float ldsT[4][16][68];

  const int tid = threadIdx.x, wave = tid >> 6, lane = tid & 63;
  const int l16 = lane & 15, lh = lane >> 4;
  const int gbase = (blockIdx.x * 4 + wave) * 4;   // 4 groups per wave
  const int type = gbase >> 12;                    // uniform per block (16 | 4096)
  const f4 fzero = {0.f, 0.f, 0.f, 0.f};

  const float* in;
  const float* W;
  if (type == 0)      { in = qrys; W = Wq; }
  else if (type == 1) { in = keys; W = Wk; }
  else                { in = vals; W = Wv; }

  bf8 wf[4][2];
#pragma unroll
  for (int ct = 0; ct < 4; ++ct)
#pragma unroll
    for (int kh = 0; kh < 2; ++kh) {
      const float* p = W + (ct*16 + l16)*64 + kh*32 + lh*8;
      bf8 t;
#pragma unroll
      for (int j = 0; j < 8; ++j) t[j] = f2bf(p[j]);
      wf[ct][kh] = t;
    }

  for (int i = 0; i < 4; ++i) {
    const int gi = (gbase + i) & 4095;
    if (type < 2) {
      const int n = gi >> 10, l = gi & 1023;
      const float* arow = in + gi*1024 + l16*64 + lh*8;
      bf8 a0, a1;
#pragma unroll
      for (int j = 0; j < 8; ++j) { a0[j] = f2bf(arow[j]); a1[j] = f2bf(arow[32 + j]); }
#pragma unroll
      for (int ct = 0; ct < 4; ++ct) {
        f4 e = fzero;
        e = mfma16(a0, wf[ct][0], e);
        e = mfma16(a1, wf[ct][1], e);
#pragma unroll
        for (int jj = 0; jj < 4; ++jj) {
          const int h = lh*4 + jj, c = ct*16 + l16;
          if (type == 0) Qp[((n*16 + h)*1024 + l)*64 + c] = f2bf(e[jj]);
          else           Kp[((n*16 + h)*1088 + l)*64 + c] = f2bf(e[jj]);
        }
      }
    } else {
      const int nh = gi >> 6, lt = (gi & 63) * 16;
      const int n = nh >> 4, h = nh & 15;
      const float* arow = in + (n*1024 + lt + l16)*1024 + h*64 + lh*8;
      bf8 a0, a1;
#pragma unroll
      for (int j = 0; j < 8; ++j) { a0[j] = f2bf(arow[j]); a1[j] = f2bf(arow[32 + j]); }
#pragma unroll
      for (int ct = 0; ct < 4; ++ct) {
        f4 e = fzero;
        e = mfma16(a0, wf[ct][0], e);
        e = mfma16(a1, wf[ct][1], e);
#pragma unroll
        for (int jj = 0; jj < 4; ++jj)
          ldsT[wave][lh*4 + jj][ct*16 + l16] = e[jj];
      }
      __syncthreads();
      short* vb = Vt + (nh*64 + lane)*1088 + lt;
      bf8 t0, t1;
#pragma unroll
      for (int j = 0; j < 8; ++j) {
        t0[j] = f2bf(ldsT[wave][j][lane]);
        t1[j] = f2bf(ldsT[wave][8 + j][lane]);
      }
      *(bf8*)vb = t0;
      *(bf8*)(vb + 8) = t1;
      __syncthreads();
    }
  }
}

// =============== Phase 1b: persistent rows, zero pads, Wo -> bf16 ===============
__global__ __launch_bounds__(256) void k_fill(
    const float* __restrict__ Wo, const float* __restrict__ pkeys,
    const float* __restrict__ pvals, short* __restrict__ ws)
{
  short* Kp = ws + KP_OFF;
  short* Vt = ws + VT_OFF;
  short* Wo_bf = ws + WO_OFF;
  const int NT = 1048576 + 65536 + 196608 + 65536 + 196608;
  for (int i = blockIdx.x*blockDim.x + threadIdx.x; i < NT; i += gridDim.x*blockDim.x) {
    int x = i;
    if (x < 1048576) { Wo_bf[x] = f2bf(Wo[x]); continue; }
    x -= 1048576;
    if (x < 65536) {
      const int d = x & 63, p = (x >> 6) & 15, nh = x >> 10;
      Kp[(nh*1088 + 1024 + p)*64 + d] = f2bf(pkeys[p*64 + d]);
      continue;
    }
    x -= 65536;
    if (x < 196608) {
      const int d = x & 63, r = x >> 6, z = r % 48, nh = r / 48;
      Kp[(nh*1088 + 1040 + z)*64 + d] = 0;
      continue;
    }
    x -= 196608;
    if (x < 65536) {
      const int d = x & 63, p = (x >> 6) & 15, nh = x >> 10;
      Vt[(nh*64 + d)*1088 + 1024 + p] = f2bf(pvals[p*64 + d]);
      continue;
    }
    x -= 65536;
    {
      const int d = x & 63, r = x >> 6, z = r % 48, nh = r / 48;
      Vt[(nh*64 + d)*1088 + 1040 + z] = 0;
    }
  }
}

// =============== Phase 2: fused talking-heads attention ===============
// grid = n(4) x qtile(64); block = 16 waves (1024 thr). Wave w IS head w
// (QK/PV phases) and q-row w (mix/exp phases) -> 4 waves/SIMD latency hiding.
// Sweep 1: Z[o,q] = sum_k exp(S). Sweep 2: recompute S, p=exp(S)/Z, mix, PV.
#define HPITCH 24
#define KPITCH 72
#define LDSE_N (16*64*HPITCH + 16)
__global__ __launch_bounds__(1024) void k_attn(
    const int* __restrict__ mask, const float* __restrict__ th_pre,
    const float* __restrict__ th_post, short* ws)
{
  const short* Qp = ws + QP_OFF;
  const short* Kp = ws + KP_OFF;
  const short* Vt = ws + VT_OFF;
  short* AO = ws + AO_OFF;

  __shared__ __align__(16) short ldsE[LDSE_N];        // [elem=(q,k)][h] bf16
  __shared__ __align__(16) short ldsA[16*16*KPITCH];  // [o][q][k] bf16

  const int tid = threadIdx.x, wave = tid >> 6, lane = tid & 63;
  const int l16 = lane & 15, lh = lane >> 4;
  const int n = blockIdx.x >> 6, qt = blockIdx.x & 63, q0 = qt * 16;
  const f4 fzero = {0.f, 0.f, 0.f, 0.f};

  // Zero ldsE ONCE (incl. pad heads 16..23 and tail): mix MFMAs read k=16..31
  // B-elements there with zero A-coefficients; 0 x NaN-garbage would poison.
  for (int i = tid; i < LDSE_N; i += 1024) ldsE[i] = 0;
  __syncthreads();

  // talking-heads A-fragments, zero-padded to K=32 (lanes lh>=2 hold zeros)
  bf8 thA[2];
  {
    bf8 z;
#pragma unroll
    for (int j = 0; j < 8; ++j) z[j] = 0;
    thA[0] = z; thA[1] = z;
    if (lh < 2) {
      const float* r0 = th_pre  + l16*16 + lh*8;
      const float* r1 = th_post + l16*16 + lh*8;
      bf8 t0, t1;
#pragma unroll
      for (int j = 0; j < 8; ++j) { t0[j] = f2bf(r0[j]); t1[j] = f2bf(r1[j]); }
      thA[0] = t0; thA[1] = t1;
    }
  }
  // mixed ALiBi slopes for o = lh*4+jj
  float mslope[4];
#pragma unroll
  for (int jj = 0; jj < 4; ++jj) {
    const int o = lh*4 + jj;
    float s = 0.f;
    for (int h = 0; h < 16; ++h) s += th_pre[o*16 + h] * exp2f(-(float)(h + 1));
    mslope[jj] = s;
  }

  // Q fragments for the wave's head (= wave), reused across all k
  bf8 qf[2];
#pragma unroll
  for (int kh = 0; kh < 2; ++kh)
    qf[kh] = *(const bf8*)(Qp + ((n*16 + wave)*1024 + q0 + l16)*64 + kh*32 + lh*8);

  const int* maskn = mask + n*1024;

  // QK for head=wave over 64 k cols; scatter E to ldsE[(q,k)][h=wave]
#define QK_STAGE() \
  { \
    const short* Kb = Kp + ((n*16 + wave)*1088 + k0 + l16)*64 + lh*8; \
    _Pragma("unroll") \
    for (int kt = 0; kt < 4; ++kt) { \
      f4 e = fzero; \
      e = mfma16(qf[0], *(const bf8*)(Kb + kt*16*64), e); \
      e = mfma16(qf[1], *(const bf8*)(Kb + kt*16*64 + 32), e); \
      _Pragma("unroll") \
      for (int jj = 0; jj < 4; ++jj) \
        ldsE[((lh*4 + jj)*64 + kt*16 + l16)*HPITCH + wave] = f2bf(e[jj]); \
    } \
  }

  // ---------------- sweep 1: Z ----------------
  const int q = wave, ig = q0 + q;   // this wave's q-row for mix phases
  float Zp[4];
#pragma unroll
  for (int a = 0; a < 4; ++a) Zp[a] = 0.f;

  for (int kb = 0; kb < 17; ++kb) {
    const int k0 = kb * 64;
    QK_STAGE();
    __syncthreads();
#pragma unroll
    for (int ks = 0; ks < 4; ++ks) {
      const int elem = q*64 + ks*16 + l16;
      bf8 Bf = *(const bf8*)(ldsE + elem*HPITCH + lh*8);
      f4 s = mfma16(thA[0], Bf, fzero);
      const int kg = k0 + ks*16 + l16;
      float ad = 0.f; bool dead;
      if (kg < 1024) { dead = (maskn[kg] == 0); ad = fabsf((float)(ig - kg)); }
      else           { dead = (kg >= 1040); }
#pragma unroll
      for (int jj = 0; jj < 4; ++jj) {
        float v = s[jj] - ad * mslope[jj];
        v = dead ? -1e4f : v;
        Zp[jj] += __expf(v * 0.03125f);
      }
    }
    __syncthreads();
  }
  // reduce Z across the 16 k-col lanes (within each lh group)
  float invZ[4];
#pragma unroll
  for (int jj = 0; jj < 4; ++jj) {
    float z = Zp[jj];
    z += __shfl_xor(z, 1); z += __shfl_xor(z, 2);
    z += __shfl_xor(z, 4); z += __shfl_xor(z, 8);
    invZ[jj] = 1.f / z;
  }

  // ---------------- sweep 2: normalize, th_post mix, PV ----------------
  f4 acc[4];
#pragma unroll
  for (int a = 0; a < 4; ++a) acc[a] = fzero;

  for (int kb = 0; kb < 17; ++kb) {
    const int k0 = kb * 64;
    QK_STAGE();
    __syncthreads();
#pragma unroll
    for (int ks = 0; ks < 4; ++ks) {
      const int elem = q*64 + ks*16 + l16;
      bf8 Bf = *(const bf8*)(ldsE + elem*HPITCH + lh*8);
      f4 s = mfma16(thA[0], Bf, fzero);
      const int kg = k0 + ks*16 + l16;
      float ad = 0.f; bool dead;
      if (kg < 1024) { dead = (maskn[kg] == 0); ad = fabsf((float)(ig - kg)); }
      else           { dead = (kg >= 1040); }
      float p[4];
#pragma unroll
      for (int jj = 0; jj < 4; ++jj) {
        float v = s[jj] - ad * mslope[jj];
        v = dead ? -1e4f : v;
        p[jj] = __expf(v * 0.03125f) * invZ[jj];
      }
      // build mix2 B-frag: lane needs p over o' = lh*8..lh*8+7 for its elem col
      const int pk0 = ((int)(unsigned short)f2bf(p[1]) << 16) | (unsigned short)f2bf(p[0]);
      const int pk1 = ((int)(unsigned short)f2bf(p[3]) << 16) | (unsigned short)f2bf(p[2]);
      const int s0 = (lh*2)*16 + l16, s1 = (lh*2 + 1)*16 + l16;
      union { int w[4]; bf8 v; } mb;
      mb.w[0] = __shfl(pk0, s0); mb.w[1] = __shfl(pk1, s0);
      mb.w[2] = __shfl(pk0, s1); mb.w[3] = __shfl(pk1, s1);
      f4 a = mfma16(thA[1], mb.v, fzero);
#pragma unroll
      for (int jj = 0; jj < 4; ++jj)
        ldsA[((lh*4 + jj)*16 + q)*KPITCH + ks*16 + l16] = f2bf(a[jj]);
    }
    __syncthreads();
    // PV for output head o = wave
    {
      const int o = wave;
      const short* Vb = Vt + (n*16 + o)*64*1088 + k0;
#pragma unroll
      for (int kkh = 0; kkh < 2; ++kkh) {
        bf8 af = *(const bf8*)(ldsA + (o*16 + l16)*KPITCH + kkh*32 + lh*8);
#pragma unroll
        for (int dt = 0; dt < 4; ++dt) {
          bf8 vf = *(const bf8*)(Vb + (dt*16 + l16)*1088 + kkh*32 + lh*8);
          acc[dt] = mfma16(af, vf, acc[dt]);
        }
      }
    }
    __syncthreads();   // ldsA reused next kb; also separates from QK ldsE write
  }

  // store attention output [n][q][o*64+d] bf16, o = wave
#pragma unroll
  for (int dt = 0; dt < 4; ++dt)
#pragma unroll
    for (int jj = 0; jj < 4; ++jj)
      AO[(n*1024 + q0 + lh*4 + jj)*1024 + wave*64 + dt*16 + l16] =
          f2bf(acc[dt][jj]);
}

// =============== Phase 3: out = AO @ Wo^T + bo (f32 out) ===============
__global__ __launch_bounds__(256) void k_out(
    const short* __restrict__ ws, const float* __restrict__ bo,
    float* __restrict__ out)
{
  const short* A  = ws + AO_OFF;
  const short* Wb = ws + WO_OFF;
  const int tid = threadIdx.x, wave = tid >> 6, lane = tid & 63;
  const int l16 = lane & 15, lh = lane >> 4;
  const int r0 = blockIdx.x*64 + wave*16, c0 = blockIdx.y*64;
  const f4 fzero = {0.f, 0.f, 0.f, 0.f};
  f4 acc[4];
#pragma unroll
  for (int ct = 0; ct < 4; ++ct) acc[ct] = fzero;

  const short* Ar = A  + (r0 + l16)*1024 + lh*8;
  const short* Wr = Wb + (c0 + l16)*1024 + lh*8;
  for (int kk = 0; kk < 1024; kk += 32) {
    bf8 af = *(const bf8*)(Ar + kk);
#pragma unroll
    for (int ct = 0; ct < 4; ++ct) {
      bf8 bf = *(const bf8*)(Wr + ct*16*1024 + kk);
      acc[ct] = mfma16(af, bf, acc[ct]);
    }
  }
#pragma unroll
  for (int ct = 0; ct < 4; ++ct) {
    const int c = c0 + ct*16 + l16;
    const float b = bo[c];
#pragma unroll
    for (int jj = 0; jj < 4; ++jj)
      out[(r0 + lh*4 + jj)*1024 + c] = acc[ct][jj] + b;
  }
}

extern "C" void kernel_launch(void* const* d_in, const int* in_sizes, int n_in,
                              void* d_out, int out_size, void* d_ws, size_t ws_size,
                              hipStream_t stream) {
  const float* vals = (const float*)d_in[0];
  const float* keys = (const float*)d_in[1];
  const float* qrys = (const float*)d_in[2];
  const int*   mask = (const int*)d_in[3];
  const float* Wv   = (const float*)d_in[4];
  const float* Wk   = (const float*)d_in[5];
  const float* Wq   = (const float*)d_in[6];
  const float* Wo   = (const float*)d_in[7];
  const float* bo   = (const float*)d_in[8];
  const float* thp  = (const float*)d_in[9];
  const float* tho  = (const float*)d_in[10];
  const float* pk   = (const float*)d_in[11];
  const float* pv   = (const float*)d_in[12];
  short* ws = (short*)d_ws;
  float* out = (float*)d_out;

  k_proj<<<768, 256, 0, stream>>>(vals, keys, qrys, Wv, Wk, Wq, ws);
  k_fill<<<512, 256, 0, stream>>>(Wo, pk, pv, ws);
  k_attn<<<256, 1024, 0, stream>>>(mask, thp, tho, ws);
  k_out<<<dim3(64, 16), 256, 0, stream>>>(ws, bo, out);
}